// Round 3
// baseline (333.143 us; speedup 1.0000x reference)
//
#include <hip/hip_runtime.h>
#include <stdint.h>

#define CIN 256
#define NH 96
#define NW 96
#define HWP (NH*NW)      // 9216
#define NA 128           // attn channels (A)
#define KS 7
#define PAD 3

typedef __attribute__((ext_vector_type(8))) short  short8;
typedef __attribute__((ext_vector_type(8))) unsigned short u16x8;
typedef __attribute__((ext_vector_type(4))) unsigned short u16x4;
typedef __attribute__((ext_vector_type(4))) float  f32x4;

__device__ __forceinline__ unsigned short f2bf(float f) {
    unsigned int u = __float_as_uint(f);
    unsigned int r = (u + 0x7fffu + ((u >> 16) & 1u)) >> 16;
    return (unsigned short)r;
}

// ---------------------------------------------------------------------------
// Phase 1: Y[b][r][p] = sum_c W2[r][c] * x[b][c][p],  r in [0,256): 0..127 = wq
// rows, 128..255 = wk rows. Output packed as bf16 pairs along r:
// ypk[bl][j][p] = (bf16(Y[2j+1]) << 16) | bf16(Y[2j]),  j in [0,128).
// Tile: BM=256 (all rows), BN=128 px, BK=32, 512 threads (8 waves, 4x2 grid of
// 64x64 wave tiles), mfma_f32_16x16x32_bf16, double-buffered LDS.
// ---------------------------------------------------------------------------
#define BN 128
#define BK 32
#define NKSTEPS (CIN/BK)   // 8
#define APITCH 40          // bf16 elements per LDS row (32 + 8 pad, 16B-mult)
#define XPITCH 40

__global__ __launch_bounds__(512) void qk_gemm(
    const float* __restrict__ x, const float* __restrict__ wq,
    const float* __restrict__ wk, unsigned int* __restrict__ ypk, int b0)
{
    __shared__ unsigned short Al[2][256*APITCH];
    __shared__ unsigned short Xl[2][BN*XPITCH];

    const int tid = threadIdx.x;
    const int bl  = blockIdx.x / (HWP/BN);   // local batch slot
    const int pt  = blockIdx.x % (HWP/BN);
    const int b   = b0 + bl;                 // global batch
    const int p0  = pt * BN;

    const int lane = tid & 63;
    const int wid  = tid >> 6;
    const int wm   = wid >> 1;   // 0..3
    const int wn   = wid & 1;    // 0..1
    const int l15  = lane & 15;
    const int l4   = lane >> 4;

    // A (weights) staging: thread -> (row, 16-col half)
    const int ar  = tid >> 1;           // 0..255
    const int ac0 = (tid & 1) * 16;     // 0 or 16
    const float* wrow = (ar < NA) ? (wq + (size_t)ar * CIN)
                                  : (wk + (size_t)(ar - NA) * CIN);

    // X staging: thread -> pixel column strip, two 4-channel quads
    const int xp   = tid & 127;
    const int cq2  = (tid >> 7) * 2;    // 0,2,4,6
    const float* xb = x + (size_t)b * CIN * HWP + p0 + xp;

    float a_stage[16];
    float x_stage[8];

    f32x4 acc[4][4];
    #pragma unroll
    for (int m = 0; m < 4; ++m)
        #pragma unroll
        for (int n = 0; n < 4; ++n)
            acc[m][n] = (f32x4){0.f, 0.f, 0.f, 0.f};

    auto LOAD = [&](int kt) {
        const f32x4* s4 = reinterpret_cast<const f32x4*>(wrow + kt*BK + ac0);
        #pragma unroll
        for (int i = 0; i < 4; ++i) {
            f32x4 v = s4[i];
            a_stage[i*4+0] = v[0]; a_stage[i*4+1] = v[1];
            a_stage[i*4+2] = v[2]; a_stage[i*4+3] = v[3];
        }
        #pragma unroll
        for (int i = 0; i < 2; ++i) {
            const int c = kt*BK + (cq2 + i)*4;
            #pragma unroll
            for (int j = 0; j < 4; ++j)
                x_stage[i*4+j] = xb[(size_t)(c + j) * HWP];
        }
    };

    auto WRITE = [&](int bi) {
        u16x8 v0, v1;
        #pragma unroll
        for (int j = 0; j < 8; ++j) { v0[j] = f2bf(a_stage[j]); v1[j] = f2bf(a_stage[8+j]); }
        *reinterpret_cast<u16x8*>(&Al[bi][ar*APITCH + ac0    ]) = v0;
        *reinterpret_cast<u16x8*>(&Al[bi][ar*APITCH + ac0 + 8]) = v1;
        #pragma unroll
        for (int i = 0; i < 2; ++i) {
            u16x4 xv;
            #pragma unroll
            for (int j = 0; j < 4; ++j) xv[j] = f2bf(x_stage[i*4+j]);
            *reinterpret_cast<u16x4*>(&Xl[bi][xp*XPITCH + (cq2 + i)*4]) = xv;
        }
    };

    auto COMPUTE = [&](int bi) {
        short8 aF[4], bF[4];
        #pragma unroll
        for (int m = 0; m < 4; ++m)
            aF[m] = *reinterpret_cast<const short8*>(
                &Al[bi][(wm*64 + m*16 + l15)*APITCH + l4*8]);
        #pragma unroll
        for (int n = 0; n < 4; ++n)
            bF[n] = *reinterpret_cast<const short8*>(
                &Xl[bi][(wn*64 + n*16 + l15)*XPITCH + l4*8]);
        #pragma unroll
        for (int m = 0; m < 4; ++m)
            #pragma unroll
            for (int n = 0; n < 4; ++n)
                acc[m][n] = __builtin_amdgcn_mfma_f32_16x16x32_bf16(
                    aF[m], bF[n], acc[m][n], 0, 0, 0);
    };

    LOAD(0);
    WRITE(0);
    for (int kt = 0; kt < NKSTEPS; ++kt) {
        if (kt + 1 < NKSTEPS) LOAD(kt + 1);   // issue global loads early
        __syncthreads();                      // buf[kt&1] ready for all waves
        COMPUTE(kt & 1);
        if (kt + 1 < NKSTEPS) WRITE((kt + 1) & 1);
    }

    // Epilogue: pack f32 pairs -> bf16x2 words.
    // acc[m][n][i] = Y[wm*64+m*16+l4*4+i][p0+wn*64+n*16+l15]
    #pragma unroll
    for (int m = 0; m < 4; ++m) {
        const int r0 = wm*64 + m*16 + l4*4;
        #pragma unroll
        for (int n = 0; n < 4; ++n) {
            const int p = p0 + wn*64 + n*16 + l15;
            unsigned int w01 = ((unsigned)f2bf(acc[m][n][1]) << 16) | f2bf(acc[m][n][0]);
            unsigned int w23 = ((unsigned)f2bf(acc[m][n][3]) << 16) | f2bf(acc[m][n][2]);
            size_t base = ((size_t)(bl*NA /*128 pair rows*/ ) + (r0 >> 1)) * HWP + p;
            ypk[base]       = w01;
            ypk[base + HWP] = w23;
        }
    }
}

// ---------------------------------------------------------------------------
// Phase 2: sim[b,h,w,ki,kj] = sum_a q[a]*k[h+ki-3, w+kj-3] + bias_h + bias_w.
// 16x16 pixel tile per block, 256 threads (1 px/thread, 49 f32 acc),
// 8 bf16 channel-pairs staged per chunk (q tile + 22x22 k halo).
// ---------------------------------------------------------------------------
#define TS 16

__global__ __launch_bounds__(256) void sim_kernel(
    const unsigned int* __restrict__ ypk, const float* __restrict__ relh,
    const float* __restrict__ relw, float* __restrict__ out, int b0)
{
    __shared__ float rhL[64][KS];
    __shared__ float rwL[64][KS];
    __shared__ unsigned int qL[8][TS][TS];
    __shared__ unsigned int kL[8][TS+6][TS+6];   // 22x22 halo

    const int tid = threadIdx.x;
    const int bl  = blockIdx.x / 36;
    const int t6  = blockIdx.x % 36;
    const int h0  = (t6 / 6) * TS;
    const int w0  = (t6 % 6) * TS;
    const int b   = b0 + bl;
    const int ly  = tid >> 4, lx = tid & 15;

    for (int i = tid; i < 64*KS; i += 256) {
        rhL[i/KS][i%KS] = relh[i];
        rwL[i/KS][i%KS] = relw[i];
    }

    float acc[KS][KS];
    #pragma unroll
    for (int i = 0; i < KS; ++i)
        #pragma unroll
        for (int j = 0; j < KS; ++j) acc[i][j] = 0.f;
    float bh[KS] = {0,0,0,0,0,0,0};
    float bw[KS] = {0,0,0,0,0,0,0};

    const unsigned int* yb = ypk + (size_t)bl * NA * HWP;

    for (int jc = 0; jc < 8; ++jc) {
        __syncthreads();   // protect LDS reuse from previous chunk's readers
        #pragma unroll
        for (int jj = 0; jj < 8; ++jj)
            qL[jj][ly][lx] = yb[(size_t)(jc*8 + jj) * HWP + (h0+ly)*NW + (w0+lx)];
        for (int idx = tid; idx < 8*22*22; idx += 256) {
            int jj = idx / 484;
            int r  = idx - jj*484;
            int hh = r / 22;
            int ww = r - hh*22;
            int gh = h0 - PAD + hh, gw = w0 - PAD + ww;
            unsigned int v = 0;
            if ((unsigned)gh < (unsigned)NH && (unsigned)gw < (unsigned)NW)
                v = yb[(size_t)(64 + jc*8 + jj) * HWP + gh*NW + gw];
            (&kL[0][0][0])[idx] = v;
        }
        __syncthreads();

        #pragma unroll
        for (int jj = 0; jj < 8; ++jj) {
            const unsigned int qv = qL[jj][ly][lx];
            const float qlo = __uint_as_float(qv << 16);
            const float qhi = __uint_as_float(qv & 0xffff0000u);
            const int jp = jc*8 + jj;   // global pair idx (channels 2jp, 2jp+1)
            if (jp < 32) {              // channels < 64 -> h-bias
                #pragma unroll
                for (int ki = 0; ki < KS; ++ki)
                    bh[ki] += qlo * rhL[2*jp][ki] + qhi * rhL[2*jp+1][ki];
            } else {                    // channels 64..127 -> w-bias
                #pragma unroll
                for (int kj = 0; kj < KS; ++kj)
                    bw[kj] += qlo * rwL[2*jp-64][kj] + qhi * rwL[2*jp-63][kj];
            }
            #pragma unroll
            for (int ki = 0; ki < KS; ++ki) {
                const unsigned int* kr = &kL[jj][ly+ki][lx];
                #pragma unroll
                for (int kj = 0; kj < KS; ++kj) {
                    const unsigned int kv = kr[kj];
                    const float klo = __uint_as_float(kv << 16);
                    const float khi = __uint_as_float(kv & 0xffff0000u);
                    acc[ki][kj] = fmaf(qlo, klo, acc[ki][kj]);
                    acc[ki][kj] = fmaf(qhi, khi, acc[ki][kj]);
                }
            }
        }
    }

    float* op = out + ((size_t)(b*NH + h0+ly)*NW + (w0+lx)) * (KS*KS);
    #pragma unroll
    for (int ki = 0; ki < KS; ++ki)
        #pragma unroll
        for (int kj = 0; kj < KS; ++kj)
            op[ki*KS + kj] = acc[ki][kj] + bh[ki] + bw[kj];
}

// ---------------------------------------------------------------------------
extern "C" void kernel_launch(void* const* d_in, const int* in_sizes, int n_in,
                              void* d_out, int out_size, void* d_ws, size_t ws_size,
                              hipStream_t stream)
{
    const float* x  = (const float*)d_in[0];
    const float* wq = (const float*)d_in[1];
    const float* wk = (const float*)d_in[2];
    const float* rh = (const float*)d_in[3];
    const float* rw = (const float*)d_in[4];
    float* out = (float*)d_out;

    const int B = 8;
    const size_t perBatch = (size_t)NA * HWP * sizeof(unsigned int);  // 4.72 MB
    int bc = (ws_size >= perBatch) ? (int)(ws_size / perBatch) : 1;
    if (bc > B) bc = B;

    unsigned int* ypk = (unsigned int*)d_ws;

    for (int b0 = 0; b0 < B; b0 += bc) {
        const int nb = (B - b0 < bc) ? (B - b0) : bc;
        qk_gemm<<<dim3(nb * (HWP/BN)), dim3(512), 0, stream>>>(x, wq, wk, ypk, b0);
        sim_kernel<<<dim3(nb * 36), dim3(256), 0, stream>>>(ypk, rh, rw, out, b0);
    }
}

// Round 5
// 176.379 us; speedup vs baseline: 1.8888x; 1.8888x over previous
//
#include <hip/hip_runtime.h>
#include <stdint.h>

#define CIN 256
#define NH 96
#define NW 96
#define HWP (NH*NW)      // 9216
#define NA 128           // attn channels (A)
#define KS 7
#define PAD 3

typedef __attribute__((ext_vector_type(8))) short  short8;
typedef __attribute__((ext_vector_type(8))) unsigned short u16x8;
typedef __attribute__((ext_vector_type(4))) unsigned short u16x4;
typedef __attribute__((ext_vector_type(4))) float  f32x4;

__device__ __forceinline__ unsigned short f2bf(float f) {
    unsigned int u = __float_as_uint(f);
    unsigned int r = (u + 0x7fffu + ((u >> 16) & 1u)) >> 16;
    return (unsigned short)r;
}
__device__ __forceinline__ unsigned int pk2(float a, float b) {
    return ((unsigned int)f2bf(b) << 16) | f2bf(a);
}
__device__ __forceinline__ int swsl(int slot, int row) { return slot ^ (row & 15); }

__device__ __forceinline__ f32x4 mfma16(short8 a, short8 b, f32x4 c) {
    return __builtin_amdgcn_mfma_f32_16x16x32_bf16(a, b, c, 0, 0, 0);
}

// ---------------------------------------------------------------------------
// Phase 1: Y[r][p] = sum_c W[r][c] x[b][c][p], r<128 = wq rows, 128..255 = wk.
// Output CHANNEL-MAJOR bf16 pairs: y[b][px][jc], jc in [0,128): pair jc =
// channels (2jc, 2jc+1); jc<64 -> q, jc>=64 -> k. 512B per pixel.
// Tile: BM=256, BN=128 px, BK=32, 512 thr (8 waves = 4x2 of 64x64).
// ---------------------------------------------------------------------------
#define BN 128
#define BK 32
#define NKSTEPS (CIN/BK)   // 8
#define APITCH 40
#define XPITCH 40

__global__ __launch_bounds__(512) void qk_gemm(
    const float* __restrict__ x, const float* __restrict__ wq,
    const float* __restrict__ wk, unsigned int* __restrict__ y, int b0)
{
    __shared__ unsigned short Al[2][256*APITCH];   // 40 KB (reused by epilogue)
    __shared__ unsigned short Xl[2][BN*XPITCH];

    const int tid = threadIdx.x;
    const int bl  = blockIdx.x / (HWP/BN);
    const int pt  = blockIdx.x % (HWP/BN);
    const int b   = b0 + bl;
    const int p0  = pt * BN;

    const int lane = tid & 63;
    const int wid  = tid >> 6;
    const int wm   = wid >> 1;   // 0..3 (row 64-block)
    const int wn   = wid & 1;    // 0..1 (px 64-block)
    const int l15  = lane & 15;
    const int l4   = lane >> 4;

    const int ar  = tid >> 1;
    const int ac0 = (tid & 1) * 16;
    const float* wrow = (ar < NA) ? (wq + (size_t)ar * CIN)
                                  : (wk + (size_t)(ar - NA) * CIN);

    const int xp   = tid & 127;
    const int cq2  = (tid >> 7) * 2;
    const float* xb = x + (size_t)b * CIN * HWP + p0 + xp;

    float a_stage[16];
    float x_stage[8];

    f32x4 acc[4][4];
    #pragma unroll
    for (int m = 0; m < 4; ++m)
        #pragma unroll
        for (int n = 0; n < 4; ++n)
            acc[m][n] = (f32x4){0.f, 0.f, 0.f, 0.f};

    auto LOAD = [&](int kt) {
        const f32x4* s4 = reinterpret_cast<const f32x4*>(wrow + kt*BK + ac0);
        #pragma unroll
        for (int i = 0; i < 4; ++i) {
            f32x4 v = s4[i];
            a_stage[i*4+0] = v[0]; a_stage[i*4+1] = v[1];
            a_stage[i*4+2] = v[2]; a_stage[i*4+3] = v[3];
        }
        #pragma unroll
        for (int i = 0; i < 2; ++i) {
            const int c = kt*BK + (cq2 + i)*4;
            #pragma unroll
            for (int j = 0; j < 4; ++j)
                x_stage[i*4+j] = xb[(size_t)(c + j) * HWP];
        }
    };

    auto WRITE = [&](int bi) {
        u16x8 v0, v1;
        #pragma unroll
        for (int j = 0; j < 8; ++j) { v0[j] = f2bf(a_stage[j]); v1[j] = f2bf(a_stage[8+j]); }
        *reinterpret_cast<u16x8*>(&Al[bi][ar*APITCH + ac0    ]) = v0;
        *reinterpret_cast<u16x8*>(&Al[bi][ar*APITCH + ac0 + 8]) = v1;
        #pragma unroll
        for (int i = 0; i < 2; ++i) {
            u16x4 xv;
            #pragma unroll
            for (int j = 0; j < 4; ++j) xv[j] = f2bf(x_stage[i*4+j]);
            *reinterpret_cast<u16x4*>(&Xl[bi][xp*XPITCH + (cq2 + i)*4]) = xv;
        }
    };

    auto COMPUTE = [&](int bi) {
        short8 aF[4], bF[4];
        #pragma unroll
        for (int m = 0; m < 4; ++m)
            aF[m] = *reinterpret_cast<const short8*>(
                &Al[bi][(wm*64 + m*16 + l15)*APITCH + l4*8]);
        #pragma unroll
        for (int n = 0; n < 4; ++n)
            bF[n] = *reinterpret_cast<const short8*>(
                &Xl[bi][(wn*64 + n*16 + l15)*XPITCH + l4*8]);
        #pragma unroll
        for (int m = 0; m < 4; ++m)
            #pragma unroll
            for (int n = 0; n < 4; ++n)
                acc[m][n] = mfma16(aF[m], bF[n], acc[m][n]);
    };

    LOAD(0);
    WRITE(0);
    for (int kt = 0; kt < NKSTEPS; ++kt) {
        if (kt + 1 < NKSTEPS) LOAD(kt + 1);
        __syncthreads();
        COMPUTE(kt & 1);
        if (kt + 1 < NKSTEPS) WRITE((kt + 1) & 1);
    }

    // ---- Epilogue: per-wave LDS transpose -> channel-major y[px][jc] ----
    // acc[m][n][i] = Y[wm*64+m*16+l4*4+i][p0+wn*64+n*16+l15]
    __syncthreads();   // all MFMA LDS reads done; reuse Al as transpose buffer
    unsigned int* buf = reinterpret_cast<unsigned int*>(&Al[0][0]) + wid * (64*20);
    unsigned int* yB  = y + (size_t)bl * (HWP*128);
    #pragma unroll
    for (int hm = 0; hm < 2; ++hm) {
        #pragma unroll
        for (int mm = 0; mm < 2; ++mm) {
            const int m = hm*2 + mm;
            #pragma unroll
            for (int n = 0; n < 4; ++n) {
                const int px  = n*16 + l15;
                const int jcl = mm*8 + l4*2;
                uint2 d;
                d.x = pk2(acc[m][n][0], acc[m][n][1]);
                d.y = pk2(acc[m][n][2], acc[m][n][3]);
                *reinterpret_cast<uint2*>(&buf[px*20 + jcl]) = d;
            }
        }
        __syncthreads();
        #pragma unroll
        for (int pass = 0; pass < 4; ++pass) {
            const int pxl = (lane >> 2) + pass*16;
            const int sl  = lane & 3;
            uint4 v = *reinterpret_cast<const uint4*>(&buf[pxl*20 + sl*4]);
            const int p = p0 + wn*64 + pxl;
            *reinterpret_cast<uint4*>(&yB[(size_t)p*128 + wm*32 + hm*16 + sl*4]) = v;
        }
        __syncthreads();
    }
}

// ---------------------------------------------------------------------------
// Phase 2 (MFMA): block = one (batch, h-row). 384 thr = 6 waves, wave = 16-px
// M-tile. Per ki: stage k-row [gi 0..111][64 pair-dw] (zeros outside pad),
// out16x32[w][gi-m0] via 2 Ntiles x 4 Ksteps; sim(w,ki,kj) = out[w][w+kj].
// Bias via one extra MFMA: B cols 0..6 = rel_h (q-pairs<32), 7..13 = rel_w.
// XOR slot-swizzle (16B granules) keeps ds_read/write_b128 conflict-free.
// ---------------------------------------------------------------------------
__global__ __launch_bounds__(384) void sim_mfma(
    const unsigned int* __restrict__ y, const float* __restrict__ relh,
    const float* __restrict__ relw, float* __restrict__ out, int b0, int nwg)
{
    __shared__ unsigned int qL[96*64];     // 24 KB
    __shared__ unsigned int kL[112*64];    // 28 KB
    __shared__ unsigned int bB[16*64];     //  4 KB
    __shared__ float extL[6][16*33];       // 12.4 KB
    __shared__ float biasL[6][16*17];      //  6.4 KB

    // bijective XCD swizzle (m204): batch b -> one XCD => k-rows stay L2-local
    const int orig = blockIdx.x;
    const int qq = nwg >> 3, rr = nwg & 7;
    const int xcd = orig & 7, off = orig >> 3;
    const int wg = (xcd < rr ? xcd*(qq+1) : rr*(qq+1) + (xcd-rr)*qq) + off;
    const int bl = wg / NH;
    const int h  = wg % NH;

    const int tid  = threadIdx.x;
    const int wid  = tid >> 6;          // 0..5 = M-tile
    const int lane = tid & 63;
    const int l15  = lane & 15, l4 = lane >> 4;
    const int m0   = wid * 16;

    const unsigned int* yb = y + (size_t)bl * (HWP*128);

    // ---- stage q row (96 px x 64 q-dwords) ----
    {
        const int sl = tid & 15, pxb = tid >> 4;   // pxb 0..23
        #pragma unroll
        for (int pass = 0; pass < 4; ++pass) {
            const int p = pxb + pass*24;
            uint4 v = *reinterpret_cast<const uint4*>(yb + (size_t)(h*NW + p)*128 + sl*4);
            *reinterpret_cast<uint4*>(&qL[p*64 + swsl(sl, p)*4]) = v;
        }
    }
    // ---- build bias B-tile: rows n (0..6: rel_h at ki=n; 7..13: rel_w) ----
    if (tid < 256) {
        const int sl = tid & 15, n = tid >> 4;
        uint4 v = {0u,0u,0u,0u};
        if (n < 14) {
            #pragma unroll
            for (int u = 0; u < 4; ++u) {
                const int jc = sl*4 + u;
                float lo = 0.f, hi = 0.f;
                if (n < 7) {
                    if (jc < 32) { lo = relh[(2*jc)*KS + n]; hi = relh[(2*jc+1)*KS + n]; }
                } else {
                    if (jc >= 32) { const int c = 2*jc - 64;
                        lo = relw[c*KS + (n-7)]; hi = relw[(c+1)*KS + (n-7)]; }
                }
                ((unsigned int*)&v)[u] = pk2(lo, hi);
            }
        }
        *reinterpret_cast<uint4*>(&bB[n*64 + swsl(sl, n)*4]) = v;
    }
    __syncthreads();

    // ---- A fragments (q), held in registers for the whole kernel ----
    short8 aF[4];
    #pragma unroll
    for (int ks = 0; ks < 4; ++ks)
        aF[ks] = *reinterpret_cast<const short8*>(
            &qL[(m0 + l15)*64 + swsl(ks*4 + l4, l15)*4]);

    // ---- bias MFMA -> biasL[wid][px][n]  (n<7: bh(ki=n); 7..13: bw(kj=n-7))
    {
        f32x4 bacc = {0.f,0.f,0.f,0.f};
        #pragma unroll
        for (int ks = 0; ks < 4; ++ks) {
            short8 bF = *reinterpret_cast<const short8*>(
                &bB[l15*64 + swsl(ks*4 + l4, l15)*4]);
            bacc = mfma16(aF[ks], bF, bacc);
        }
        #pragma unroll
        for (int i = 0; i < 4; ++i)
            biasL[wid][(l4*4 + i)*17 + l15] = bacc[i];
    }
    // (first __syncthreads in the ki-loop orders biasL dump before any read)

    for (int ki = 0; ki < KS; ++ki) {
        __syncthreads();                       // prior kL/extL readers done
        const int r = h + ki - PAD;
        {
            const int sl = tid & 15, gib = tid >> 4;
            #pragma unroll
            for (int pass = 0; pass < 5; ++pass) {
                const int g = gib + pass*24;
                if (g < 112) {
                    uint4 v = {0u,0u,0u,0u};
                    const int p = g - PAD;
                    if ((unsigned)r < (unsigned)NH && (unsigned)p < (unsigned)NW)
                        v = *reinterpret_cast<const uint4*>(
                            yb + (size_t)(r*NW + p)*128 + 64 + sl*4);
                    *reinterpret_cast<uint4*>(&kL[g*64 + swsl(sl, g)*4]) = v;
                }
            }
        }
        __syncthreads();                       // kL ready

        f32x4 a0 = {0.f,0.f,0.f,0.f}, a1 = {0.f,0.f,0.f,0.f};
        #pragma unroll
        for (int ks = 0; ks < 4; ++ks) {
            short8 b0f = *reinterpret_cast<const short8*>(
                &kL[(m0 + l15)*64      + swsl(ks*4 + l4, l15)*4]);
            short8 b1f = *reinterpret_cast<const short8*>(
                &kL[(m0 + 16 + l15)*64 + swsl(ks*4 + l4, l15)*4]);
            a0 = mfma16(aF[ks], b0f, a0);
            a1 = mfma16(aF[ks], b1f, a1);
        }
        // dump: ext[M][N], M=l4*4+i, N=l15 (+16 for tile 1)
        #pragma unroll
        for (int i = 0; i < 4; ++i) {
            extL[wid][(l4*4 + i)*33 + l15]      = a0[i];
            extL[wid][(l4*4 + i)*33 + 16 + l15] = a1[i];
        }
        __syncthreads();                       // dump visible

        // extract: lane (px=l15, kj=l4 and l4+4): sim = ext[px][px+kj]+bias
        {
            const int px = l15;
            const float* eb = extL[wid];
            const float* bb = biasL[wid];
            const float bki = bb[px*17 + ki];
            const size_t ob = ((size_t)((b0 + bl)*NH + h)*NW + m0 + px)*(KS*KS) + ki*KS;
            const int kj1 = l4;
            out[ob + kj1] = eb[px*33 + px + kj1] + bki + bb[px*17 + 7 + kj1];
            if (l4 < 3) {
                const int kj2 = l4 + 4;
                out[ob + kj2] = eb[px*33 + px + kj2] + bki + bb[px*17 + 7 + kj2];
            }
        }
    }
}

// ---------------------------------------------------------------------------
extern "C" void kernel_launch(void* const* d_in, const int* in_sizes, int n_in,
                              void* d_out, int out_size, void* d_ws, size_t ws_size,
                              hipStream_t stream)
{
    const float* x  = (const float*)d_in[0];
    const float* wq = (const float*)d_in[1];
    const float* wk = (const float*)d_in[2];
    const float* rh = (const float*)d_in[3];
    const float* rw = (const float*)d_in[4];
    float* out = (float*)d_out;

    const int B = 8;
    const size_t perBatch = (size_t)HWP * 128 * sizeof(unsigned int);  // 4.72 MB
    int bc = (ws_size >= perBatch) ? (int)(ws_size / perBatch) : 1;
    if (bc > B) bc = B;

    unsigned int* y = (unsigned int*)d_ws;

    for (int b0 = 0; b0 < B; b0 += bc) {
        const int nb = (B - b0 < bc) ? (B - b0) : bc;
        qk_gemm<<<dim3(nb * (HWP/BN)), dim3(512), 0, stream>>>(x, wq, wk, y, b0);
        const int nwg = nb * NH;
        sim_mfma<<<dim3(nwg), dim3(384), 0, stream>>>(y, rh, rw, out, b0, nwg);
    }
}

// Round 6
// 165.320 us; speedup vs baseline: 2.0151x; 1.0669x over previous
//
#include <hip/hip_runtime.h>
#include <stdint.h>

#define CIN 256
#define NH 96
#define NW 96
#define HWP (NH*NW)      // 9216
#define NA 128           // attn channels (A)
#define KS 7
#define PAD 3

typedef unsigned int u32;
typedef __attribute__((ext_vector_type(8))) short  short8;
typedef __attribute__((ext_vector_type(4))) unsigned short u16x4;
typedef __attribute__((ext_vector_type(4))) float  f32x4;

__device__ __forceinline__ unsigned short f2bf(float f) {
    unsigned int u = __float_as_uint(f);
    unsigned int r = (u + 0x7fffu + ((u >> 16) & 1u)) >> 16;
    return (unsigned short)r;
}
__device__ __forceinline__ unsigned int pk2(float a, float b) {
    return ((unsigned int)f2bf(b) << 16) | f2bf(a);
}
__device__ __forceinline__ int swsl(int slot, int row) { return slot ^ (row & 15); }

__device__ __forceinline__ f32x4 mfma16(short8 a, short8 b, f32x4 c) {
    return __builtin_amdgcn_mfma_f32_16x16x32_bf16(a, b, c, 0, 0, 0);
}
__device__ __forceinline__ short8 as_s8(uint4 v) {
    union { uint4 u; short8 s; } cv; cv.u = v; return cv.s;
}
// async global->LDS, 16B per lane; dest = wave-uniform base + lane*16
__device__ __forceinline__ void gl_lds16(const u32* g, u32* l) {
    __builtin_amdgcn_global_load_lds(
        (const __attribute__((address_space(1))) u32*)g,
        (__attribute__((address_space(3))) u32*)l, 16, 0, 0);
}

// ---------------------------------------------------------------------------
// wprep: build preW = per-K-step swizzled bf16 LDS images of W2=[wq;wk].
// Image kt: row r (0..255), phys 16B slot s (0..3) at byte r*64+s*16 holds
// cols kt*32 + (s^(r&3))*8 .. +7 (XOR slot swizzle -> conflict-free ds_read).
// ---------------------------------------------------------------------------
__global__ __launch_bounds__(256) void wprep(
    const float* __restrict__ wq, const float* __restrict__ wk,
    u32* __restrict__ preW)
{
    const int id  = blockIdx.x * 256 + threadIdx.x;   // 0..8191
    const int kt  = id >> 10;
    const int rem = id & 1023;
    const int row = rem >> 2;
    const int s   = rem & 3;
    const int g   = s ^ (row & 3);
    const float* wr = (row < NA) ? (wq + (size_t)row * CIN)
                                 : (wk + (size_t)(row - NA) * CIN);
    const float* src = wr + kt*32 + g*8;
    uint4 d;
    d.x = pk2(src[0], src[1]);
    d.y = pk2(src[2], src[3]);
    d.z = pk2(src[4], src[5]);
    d.w = pk2(src[6], src[7]);
    *reinterpret_cast<uint4*>(preW + (size_t)id * 4) = d;
}

// ---------------------------------------------------------------------------
// Phase 1: Y[r][p] = sum_c W2[r][c] x[b][c][p]. Output CHANNEL-MAJOR bf16
// pairs y[b][px][jc], jc<64 -> q, jc>=64 -> k. BM=256, BN=128 px, BK=32,
// 512 thr (8 waves = 4x2 of 64x64). A staged via global_load_lds from preW
// (zero VALU); X staged f32->bf16 (8 cvt/thread/step). Double-buffered.
// ---------------------------------------------------------------------------
#define BN 128
#define BK 32
#define NKSTEPS (CIN/BK)   // 8
#define ADW 4096           // dwords per A image (256 rows * 16 dw)
#define XDW 2560           // dwords per X buffer (128 px * 20 dw)

__global__ __launch_bounds__(512) void qk_gemm(
    const float* __restrict__ x, const u32* __restrict__ preW,
    u32* __restrict__ y, int b0)
{
    __shared__ u32 arena[13312];   // 52KB: A0 A1 X0 X1; epilogue overlays

    const int tid = threadIdx.x;
    const int bl  = blockIdx.x / (HWP/BN);
    const int pt  = blockIdx.x % (HWP/BN);
    const int b   = b0 + bl;
    const int p0  = pt * BN;

    const int lane = tid & 63;
    const int wid  = tid >> 6;
    const int wm   = wid >> 1;   // 0..3 (row 64-block)
    const int wn   = wid & 1;    // 0..1 (px 64-block)
    const int l15  = lane & 15;
    const int l4   = lane >> 4;
    const int xr   = (l4 ^ (l15 & 3)) << 2;   // A slot dword offset

    const int xp   = tid & 127;
    const int cq2  = (tid >> 7) * 2;
    const float* xb = x + (size_t)b * CIN * HWP + p0 + xp;

    float x_stage[8];
    f32x4 acc[4][4];
    #pragma unroll
    for (int m = 0; m < 4; ++m)
        #pragma unroll
        for (int n = 0; n < 4; ++n)
            acc[m][n] = (f32x4){0.f, 0.f, 0.f, 0.f};

    auto GLLDSA = [&](int kt, int bi) {    // 2 x 1KB per wave
        const u32* src = preW + kt*ADW + wid*512 + lane*4;
        u32* dst = arena + bi*ADW + wid*512;
        gl_lds16(src, dst);
        gl_lds16(src + 256, dst + 256);
    };
    auto LOADX = [&](int kt) {
        #pragma unroll
        for (int i = 0; i < 2; ++i) {
            const int c = kt*BK + (cq2 + i)*4;
            #pragma unroll
            for (int j = 0; j < 4; ++j)
                x_stage[i*4+j] = xb[(size_t)(c + j) * HWP];
        }
    };
    auto WRITEX = [&](int bi) {
        unsigned short* Xu = (unsigned short*)(arena + 8192 + bi*XDW);
        #pragma unroll
        for (int i = 0; i < 2; ++i) {
            u16x4 xv;
            #pragma unroll
            for (int j = 0; j < 4; ++j) xv[j] = f2bf(x_stage[i*4+j]);
            *reinterpret_cast<u16x4*>(Xu + xp*40 + (cq2 + i)*4) = xv;
        }
    };
    auto COMPUTE = [&](int bi) {
        const u32* Ab = arena + bi*ADW;
        const unsigned short* Xu = (const unsigned short*)(arena + 8192 + bi*XDW);
        short8 aF[4], bF[4];
        #pragma unroll
        for (int m = 0; m < 4; ++m)
            aF[m] = *reinterpret_cast<const short8*>(
                Ab + (wm*64 + m*16 + l15)*16 + xr);
        #pragma unroll
        for (int n = 0; n < 4; ++n)
            bF[n] = *reinterpret_cast<const short8*>(
                Xu + (wn*64 + n*16 + l15)*40 + l4*8);
        #pragma unroll
        for (int m = 0; m < 4; ++m)
            #pragma unroll
            for (int n = 0; n < 4; ++n)
                acc[m][n] = mfma16(aF[m], bF[n], acc[m][n]);
    };

    GLLDSA(0, 0); LOADX(0); WRITEX(0);
    for (int kt = 0; kt < NKSTEPS; ++kt) {
        __syncthreads();   // drains vmcnt (A gllds) + lgkm (X writes) of buf kt&1
        if (kt + 1 < NKSTEPS) { GLLDSA(kt + 1, (kt + 1) & 1); LOADX(kt + 1); }
        COMPUTE(kt & 1);
        if (kt + 1 < NKSTEPS) WRITEX((kt + 1) & 1);
    }

    // ---- Epilogue: per-wave LDS transpose -> channel-major y[px][jc] ----
    // acc[m][n][i] = Y[wm*64+m*16+l4*4+i][p0+wn*64+n*16+l15]
    __syncthreads();   // all buf reads done; overlay arena as transpose buf
    u32* buf = arena + wid * 1280;   // wave-private 64px x 20dw
    u32* yB  = y + (size_t)bl * (HWP*128);
    #pragma unroll
    for (int hm = 0; hm < 2; ++hm) {
        #pragma unroll
        for (int mm = 0; mm < 2; ++mm) {
            const int m = hm*2 + mm;
            #pragma unroll
            for (int n = 0; n < 4; ++n) {
                const int px  = n*16 + l15;
                const int jcl = mm*8 + l4*2;
                uint2 d;
                d.x = pk2(acc[m][n][0], acc[m][n][1]);
                d.y = pk2(acc[m][n][2], acc[m][n][3]);
                *reinterpret_cast<uint2*>(&buf[px*20 + jcl]) = d;
            }
        }
        // wave-private buffer: DS ops are in-order per wave, no barrier needed
        #pragma unroll
        for (int pass = 0; pass < 4; ++pass) {
            const int pxl = (lane >> 2) + pass*16;
            const int sl  = lane & 3;
            uint4 v = *reinterpret_cast<const uint4*>(&buf[pxl*20 + sl*4]);
            const int p = p0 + wn*64 + pxl;
            *reinterpret_cast<uint4*>(&yB[(size_t)p*128 + wm*32 + hm*16 + sl*4]) = v;
        }
    }
}

// ---------------------------------------------------------------------------
// Phase 2 (MFMA, barrier-free ki loop): block = (batch, h-row), 6 waves,
// wave = 16-px M-tile. A-frags (q) and B-frags (k) gathered DIRECTLY from
// global y (L1/L2-resident); extract + bias via wave-private LDS. Single
// __syncthreads total (after shared bias B-tile init).
// ---------------------------------------------------------------------------
__global__ __launch_bounds__(384) void sim_mfma(
    const u32* __restrict__ y, const float* __restrict__ relh,
    const float* __restrict__ relw, float* __restrict__ out, int b0, int nwg)
{
    __shared__ u32 bB[16*64];              //  4 KB (shared, read-only after init)
    __shared__ float extL[6][16*33];       // 12.7 KB (wave-private slices)
    __shared__ float biasL[6][16*17];      //  6.5 KB (wave-private slices)

    // bijective XCD swizzle (m204): batch stays on one XCD -> y L2-local
    const int orig = blockIdx.x;
    const int qq = nwg >> 3, rr = nwg & 7;
    const int xcd = orig & 7, off = orig >> 3;
    const int wg = (xcd < rr ? xcd*(qq+1) : rr*(qq+1) + (xcd-rr)*qq) + off;
    const int bl = wg / NH;
    const int h  = wg % NH;

    const int tid  = threadIdx.x;
    const int wid  = tid >> 6;          // 0..5 = M-tile
    const int lane = tid & 63;
    const int l15  = lane & 15, l4 = lane >> 4;
    const int m0   = wid * 16;

    const u32* yb = y + (size_t)bl * (HWP*128);

    // ---- bias B-tile: col n<7 = rel_h[.,n] on q-pairs<32; 7..13 = rel_w ----
    if (tid < 256) {
        const int sl = tid & 15, n = tid >> 4;
        uint4 v = {0u,0u,0u,0u};
        if (n < 14) {
            #pragma unroll
            for (int u = 0; u < 4; ++u) {
                const int jc = sl*4 + u;
                float lo = 0.f, hi = 0.f;
                if (n < 7) {
                    if (jc < 32) { lo = relh[(2*jc)*KS + n]; hi = relh[(2*jc+1)*KS + n]; }
                } else {
                    if (jc >= 32) { const int c = 2*jc - 64;
                        lo = relw[c*KS + (n-7)]; hi = relw[(c+1)*KS + (n-7)]; }
                }
                ((unsigned int*)&v)[u] = pk2(lo, hi);
            }
        }
        *reinterpret_cast<uint4*>(&bB[n*64 + swsl(sl, n)*4]) = v;
    }
    __syncthreads();   // the only block-wide barrier

    // ---- A fragments (q) direct from global ----
    short8 aF[4];
    const u32* qrow = yb + (size_t)(h*NW + m0 + l15) * 128;
    #pragma unroll
    for (int ks = 0; ks < 4; ++ks)
        aF[ks] = as_s8(*reinterpret_cast<const uint4*>(qrow + (ks*4 + l4)*4));

    // ---- bias MFMA -> biasL[wid][px][n] (n<7: bh(ki=n); 7..13: bw(kj=n-7))
    {
        f32x4 bacc = {0.f,0.f,0.f,0.f};
        #pragma unroll
        for (int ks = 0; ks < 4; ++ks) {
            short8 bF = *reinterpret_cast<const short8*>(
                &bB[l15*64 + swsl(ks*4 + l4, l15)*4]);
            bacc = mfma16(aF[ks], bF, bacc);
        }
        #pragma unroll
        for (int i = 0; i < 4; ++i)
            biasL[wid][(l4*4 + i)*17 + l15] = bacc[i];
    }

    const int pA = m0 + l15 - PAD;        // tile0 source px (col N=l15)
    const int pB = m0 + 16 + l15 - PAD;   // tile1 source px (col N=16+l15)
    const bool okA = (unsigned)pA < (unsigned)NW;
    const bool okB = (unsigned)pB < (unsigned)NW;

    for (int ki = 0; ki < KS; ++ki) {
        const int r = h + ki - PAD;
        const bool rok = (unsigned)r < (unsigned)NH;
        const u32* rbase = yb + (size_t)r * NW * 128 + 64;   // k-half
        f32x4 a0 = {0.f,0.f,0.f,0.f}, a1 = {0.f,0.f,0.f,0.f};
        #pragma unroll
        for (int ks = 0; ks < 4; ++ks) {
            uint4 v0 = {0u,0u,0u,0u}, v1 = {0u,0u,0u,0u};
            if (rok && okA)
                v0 = *reinterpret_cast<const uint4*>(rbase + (size_t)pA*128 + (ks*4 + l4)*4);
            if (rok && okB)
                v1 = *reinterpret_cast<const uint4*>(rbase + (size_t)pB*128 + (ks*4 + l4)*4);
            a0 = mfma16(aF[ks], as_s8(v0), a0);
            a1 = mfma16(aF[ks], as_s8(v1), a1);
        }
        // wave-private dump (DS in-order per wave; compiler inserts lgkm waits)
        #pragma unroll
        for (int i = 0; i < 4; ++i) {
            extL[wid][(l4*4 + i)*33 + l15]      = a0[i];
            extL[wid][(l4*4 + i)*33 + 16 + l15] = a1[i];
        }
        // extract diagonal band: lane (px=l15, kj=l4 / l4+4)
        const float* eb = extL[wid];
        const float* bb = biasL[wid];
        const float bki = bb[l15*17 + ki];
        const size_t ob = ((size_t)((b0 + bl)*NH + h)*NW + m0 + l15)*(KS*KS) + ki*KS;
        out[ob + l4] = eb[l15*33 + l15 + l4] + bki + bb[l15*17 + 7 + l4];
        if (l4 < 3)
            out[ob + l4 + 4] = eb[l15*33 + l15 + l4 + 4] + bki + bb[l15*17 + 11 + l4];
    }
}

// ---------------------------------------------------------------------------
extern "C" void kernel_launch(void* const* d_in, const int* in_sizes, int n_in,
                              void* d_out, int out_size, void* d_ws, size_t ws_size,
                              hipStream_t stream)
{
    const float* x  = (const float*)d_in[0];
    const float* wq = (const float*)d_in[1];
    const float* wk = (const float*)d_in[2];
    const float* rh = (const float*)d_in[3];
    const float* rw = (const float*)d_in[4];
    float* out = (float*)d_out;

    const int B = 8;
    u32* preW = (u32*)d_ws;                 // 128 KB (8 x 16KB images)
    u32* y    = (u32*)d_ws + 32768;
    const size_t perBatch = (size_t)HWP * 128 * sizeof(u32);  // 4.72 MB
    size_t avail = ws_size > 131072 ? ws_size - 131072 : 0;
    int bc = (avail >= perBatch) ? (int)(avail / perBatch) : 1;
    if (bc > B) bc = B;

    wprep<<<dim3(32), dim3(256), 0, stream>>>(wq, wk, preW);

    for (int b0 = 0; b0 < B; b0 += bc) {
        const int nb = (B - b0 < bc) ? (B - b0) : bc;
        qk_gemm<<<dim3(nb * (HWP/BN)), dim3(512), 0, stream>>>(x, preW, y, b0);
        const int nwg = nb * NH;
        sim_mfma<<<dim3(nwg), dim3(384), 0, stream>>>(y, rh, rw, out, b0, nwg);
    }
}